// Round 3
// baseline (2893.572 us; speedup 1.0000x reference)
//
#include <hip/hip_runtime.h>

// RandomMFGL: out[o][g] = (1/4) * sum_n [ (A[n] @ x) @ W[n] + b[n] ]
// A: [4][4096][16384] fp32 = 1.07 GB streamed once -> HBM-bound, floor ~175us.
//
// k_main layout (R3): 4 lanes per row (p=lane&3 owns bytes p*16..p*16+15 of each
// 64B step), 16 rows per wave -> every A-load instruction covers 16 fully-dense
// 64B segments (coalesced, cheap TA). x operands are per-lane vector loads
// (float4, only 4 distinct addresses/inst, 16-way HW broadcast, L1-resident) --
// no reliance on compiler scalarization, no LDS, no barriers.
// Per 1 KB of A: 1 A-load + 16 x-loads + 64 FMA insts -> TA ~50%, VALU ~35%
// at HBM rate; HBM is the only saturated pipe.
// Epilogue per split-chunk: 2-step shfl_xor reduce over the 4 lanes of a row.

#define N_ENS 4
#define N_OUT 4096
#define N_IN  16384
#define ROWS  (N_ENS * N_OUT)      // 16384 rows (row = n*4096 + o)
#define GSPLIT 8                   // split-K factor
#define ICHUNK (N_IN / GSPLIT)     // 2048 i per (row-tile, split)
#define NSTEP  (ICHUNK / 16)       // 128 steps of 16 i

// ------------- kernel 1: hp[split][row][f] = sum_{i in chunk} A[row][i] * x[i][f] -------------
__global__ __launch_bounds__(256, 4) void k_main(const float* __restrict__ A,
                                                 const float* __restrict__ x,
                                                 float* __restrict__ hp) {
    const int split   = blockIdx.x & (GSPLIT - 1);  // 0..7
    const int rowtile = blockIdx.x >> 3;            // 0..255 (64 rows each)
    const int tid  = threadIdx.x;
    const int wave = tid >> 6;                      // 0..3
    const int r    = (tid >> 2) & 15;               // row within wave
    const int p    = tid & 3;                       // quad within 64B row-step

    const int row = rowtile * 64 + wave * 16 + r;
    const int i0  = split * ICHUNK;

    const float* Ap = A + (size_t)row * N_IN + i0 + (p << 2);

    float acc[16];
#pragma unroll
    for (int f = 0; f < 16; ++f) acc[f] = 0.0f;

    for (int s = 0; s < NSTEP; ++s) {
        // lane's 4 A values: i = i0 + s*16 + p*4 + q
        float4 av = *(const float4*)(Ap + s * 16);
        const float* xb = x + ((size_t)(i0 + s * 16 + (p << 2)) << 4);
        const float* af = (const float*)&av;
#pragma unroll
        for (int q = 0; q < 4; ++q) {
            const float a = af[q];
#pragma unroll
            for (int j = 0; j < 4; ++j) {
                float4 xv = *(const float4*)(xb + (q << 4) + (j << 2));
                acc[4 * j + 0] = fmaf(a, xv.x, acc[4 * j + 0]);
                acc[4 * j + 1] = fmaf(a, xv.y, acc[4 * j + 1]);
                acc[4 * j + 2] = fmaf(a, xv.z, acc[4 * j + 2]);
                acc[4 * j + 3] = fmaf(a, xv.w, acc[4 * j + 3]);
            }
        }
    }

    // reduce over the 4 lanes sharing this row (butterfly keeps all lanes valid)
#pragma unroll
    for (int f = 0; f < 16; ++f) {
        acc[f] += __shfl_xor(acc[f], 1, 64);
        acc[f] += __shfl_xor(acc[f], 2, 64);
    }

    // lane (r,p) writes f-quad p of its row: 16 dense 64B segments per wave
    float4 v;
    if      (p == 0) v = make_float4(acc[0],  acc[1],  acc[2],  acc[3]);
    else if (p == 1) v = make_float4(acc[4],  acc[5],  acc[6],  acc[7]);
    else if (p == 2) v = make_float4(acc[8],  acc[9],  acc[10], acc[11]);
    else             v = make_float4(acc[12], acc[13], acc[14], acc[15]);
    *(float4*)(hp + (((size_t)split * ROWS + row) << 4) + (p << 2)) = v;
}

// ------------- kernel 2: h[row][f] = sum_split hp[split][row][f] -------------
__global__ __launch_bounds__(256) void k_hsum(const float* __restrict__ hp,
                                              float* __restrict__ h) {
    int t = blockIdx.x * 256 + threadIdx.x;   // 0 .. 262143
    float s = 0.0f;
#pragma unroll
    for (int sp = 0; sp < GSPLIT; ++sp)
        s += hp[(size_t)sp * (ROWS * 16) + t];
    h[t] = s;
}

// ------------- kernel 3: out[o][g] = 0.25 * sum_n (sum_f h[n][o][f]*W[n][f][g] + b[n][g]) -------------
__global__ __launch_bounds__(256) void k_out(const float* __restrict__ h,
                                             const float* __restrict__ Ws,
                                             const float* __restrict__ bs,
                                             float* __restrict__ out) {
    __shared__ float Wsm[N_ENS * 16 * 16];
    __shared__ float bsm[N_ENS * 16];
    int tid = threadIdx.x;
#pragma unroll
    for (int r = 0; r < 4; ++r) Wsm[tid + 256 * r] = Ws[tid + 256 * r];
    if (tid < 64) bsm[tid] = bs[tid];
    __syncthreads();

    int idx = blockIdx.x * 256 + tid;   // 0..65535
    int o = idx >> 4;
    int gg = idx & 15;
    float s = 0.0f;
#pragma unroll
    for (int n = 0; n < N_ENS; ++n) {
        const float* hr = h + ((size_t)(n * N_OUT + o) << 4);
        float t = 0.0f;
#pragma unroll
        for (int f = 0; f < 16; ++f)
            t = fmaf(hr[f], Wsm[n * 256 + f * 16 + gg], t);
        s += t + bsm[n * 16 + gg];
    }
    out[idx] = 0.25f * s;
}

extern "C" void kernel_launch(void* const* d_in, const int* in_sizes, int n_in,
                              void* d_out, int out_size, void* d_ws, size_t ws_size,
                              hipStream_t stream) {
    const float* x  = (const float*)d_in[0];   // [1, 16384, 16]
    const float* As = (const float*)d_in[1];   // [4, 4096, 16384]
    const float* Ws = (const float*)d_in[2];   // [4, 16, 16]
    const float* bs = (const float*)d_in[3];   // [4, 16]
    float* out = (float*)d_out;                // [1, 4096, 16]

    float* hp = (float*)d_ws;                                      // 8 MB: [8][16384][16]
    float* h  = (float*)((char*)d_ws + (size_t)8 * 1024 * 1024);   // 1 MB: [16384][16]

    // hp/h fully overwritten every call -> no memset needed despite 0xAA poison.
    k_main<<<256 * GSPLIT, 256, 0, stream>>>(As, x, hp);
    k_hsum<<<(ROWS * 16) / 256, 256, 0, stream>>>(hp, h);
    k_out<<<(N_OUT * 16) / 256, 256, 0, stream>>>(h, Ws, bs, out);
}

// Round 4
// 1681.613 us; speedup vs baseline: 1.7207x; 1.7207x over previous
//
#include <hip/hip_runtime.h>

// RandomMFGL: out[o][g] = (1/4) * sum_n [ (A[n] @ x) @ W[n] + b[n] ]
// A: [4][4096][16384] fp32 = 1.07 GB streamed once -> HBM-bound, floor ~175us.
//
// R4 design (post-mortem of R3's latency collapse at VGPR=32):
//  - Wave tile 64 rows x 16 f; lane owns 4 rows x 4 f (register rank-1 tile).
//  - x chunk (512 i x 16 f = 32 KB) staged to LDS ONCE per block; lane x reads
//    are ds_read_b128, 4 distinct addrs x 4 banks = 16 banks + 16-way broadcast
//    -> conflict-free, short latency (no global per-lane x loads to serialize).
//  - A loads: 4 float4/step with EXPLICIT next-step prefetch regs (a_nxt) and
//    unroll-2 buffer rotation -> multiple A loads in flight, no vmcnt(0) chains.
//  - Per wave-step (1 KB unique A): VALU 128 cyc, LDS 48 cyc, 4 VMEM inst
//    -> at 9.8 B/cyc/CU HBM rate: VALU ~31%, LDS ~46%, HBM saturated.
//  - Split-K=32 deterministic partials in ws, then tree-reduce + W/b/mean.

#define N_ENS 4
#define N_OUT 4096
#define N_IN  16384
#define ROWS  (N_ENS * N_OUT)      // 16384 rows (row = n*4096 + o)
#define GSPLIT 32                  // split-K factor
#define ICHUNK (N_IN / GSPLIT)     // 512 i per (row-block, split)
#define NSTEP  (ICHUNK / 4)        // 128 steps of 4 i

// ------------- kernel 1: hp[split][row][f] = sum_{i in chunk} A[row][i] * x[i][f] -------------
__global__ __launch_bounds__(256, 4) void k_main(const float* __restrict__ A,
                                                 const float* __restrict__ x,
                                                 float* __restrict__ hp) {
    __shared__ float xs[ICHUNK * 16];               // 32 KB: x[i0..i0+512)[0..16)

    const int split   = blockIdx.x & (GSPLIT - 1);  // 0..31
    const int rowblk  = blockIdx.x >> 5;            // 0..63 (256 rows each)
    const int tid  = threadIdx.x;
    const int i0   = split * ICHUNK;

    // ---- stage x chunk (contiguous 32 KB) into LDS, coalesced ----
    {
        const float4* xg = (const float4*)(x + (size_t)i0 * 16);
        float4* xs4 = (float4*)xs;
#pragma unroll
        for (int j = 0; j < 8; ++j)
            xs4[tid + 256 * j] = xg[tid + 256 * j];
    }
    __syncthreads();

    const int wave  = tid >> 6;                     // 0..3
    const int lane  = tid & 63;
    const int o_sub = lane & 15;                    // row within wave tile
    const int f_sub = lane >> 4;                    // f-quad (4 consecutive f)
    const int rowbase = rowblk * 256 + wave * 64 + o_sub;   // rows rowbase+16k

    const float* Ap = A + (size_t)rowbase * N_IN + i0;

    float4 acc[4];
#pragma unroll
    for (int k = 0; k < 4; ++k) acc[k] = make_float4(0.f, 0.f, 0.f, 0.f);

    float4 a_cur[4], a_nxt[4];
#pragma unroll
    for (int k = 0; k < 4; ++k)
        a_cur[k] = *(const float4*)(Ap + (size_t)k * 16 * N_IN);

#pragma unroll 2
    for (int s = 0; s < NSTEP; ++s) {
        // prefetch next step's A (4 rows x 4 i) -- stays in flight over the FMAs
        if (s + 1 < NSTEP) {
#pragma unroll
            for (int k = 0; k < 4; ++k)
                a_nxt[k] = *(const float4*)(Ap + (size_t)k * 16 * N_IN + (s + 1) * 4);
        }

        // lane's x operands: x[s*4+q][f_sub*4 .. +3], conflict-free b128 reads
        float4 xv[4];
#pragma unroll
        for (int q = 0; q < 4; ++q)
            xv[q] = *(const float4*)&xs[(s * 4 + q) * 16 + f_sub * 4];

#pragma unroll
        for (int k = 0; k < 4; ++k) {
            const float* af = (const float*)&a_cur[k];
#pragma unroll
            for (int q = 0; q < 4; ++q) {
                const float a = af[q];
                acc[k].x = fmaf(a, xv[q].x, acc[k].x);
                acc[k].y = fmaf(a, xv[q].y, acc[k].y);
                acc[k].z = fmaf(a, xv[q].z, acc[k].z);
                acc[k].w = fmaf(a, xv[q].w, acc[k].w);
            }
        }

#pragma unroll
        for (int k = 0; k < 4; ++k) a_cur[k] = a_nxt[k];
    }

    // lane (o_sub, f_sub) holds h-partials for rows rowbase+16k, f-quad f_sub.
    // Per k, wave writes 16 rows x 64 B = 1 KB contiguous. No atomics.
#pragma unroll
    for (int k = 0; k < 4; ++k) {
        int row = rowbase + 16 * k;
        *(float4*)(hp + (((size_t)split * ROWS + row) << 4) + (f_sub << 2)) = acc[k];
    }
}

// ------------- kernel 2: h[row][f] = sum_split hp[split][row][f] -------------
__global__ __launch_bounds__(256) void k_hsum(const float* __restrict__ hp,
                                              float* __restrict__ h) {
    int t = blockIdx.x * 256 + threadIdx.x;   // 0 .. 262143
    float s = 0.0f;
#pragma unroll
    for (int sp = 0; sp < GSPLIT; ++sp)
        s += hp[(size_t)sp * (ROWS * 16) + t];
    h[t] = s;
}

// ------------- kernel 3: out[o][g] = 0.25 * sum_n (sum_f h[n][o][f]*W[n][f][g] + b[n][g]) -------------
__global__ __launch_bounds__(256) void k_out(const float* __restrict__ h,
                                             const float* __restrict__ Ws,
                                             const float* __restrict__ bs,
                                             float* __restrict__ out) {
    __shared__ float Wsm[N_ENS * 16 * 16];
    __shared__ float bsm[N_ENS * 16];
    int tid = threadIdx.x;
#pragma unroll
    for (int r = 0; r < 4; ++r) Wsm[tid + 256 * r] = Ws[tid + 256 * r];
    if (tid < 64) bsm[tid] = bs[tid];
    __syncthreads();

    int idx = blockIdx.x * 256 + tid;   // 0..65535
    int o = idx >> 4;
    int gg = idx & 15;
    float s = 0.0f;
#pragma unroll
    for (int n = 0; n < N_ENS; ++n) {
        const float* hr = h + ((size_t)(n * N_OUT + o) << 4);
        float t = 0.0f;
#pragma unroll
        for (int f = 0; f < 16; ++f)
            t = fmaf(hr[f], Wsm[n * 256 + f * 16 + gg], t);
        s += t + bsm[n * 16 + gg];
    }
    out[idx] = 0.25f * s;
}

extern "C" void kernel_launch(void* const* d_in, const int* in_sizes, int n_in,
                              void* d_out, int out_size, void* d_ws, size_t ws_size,
                              hipStream_t stream) {
    const float* x  = (const float*)d_in[0];   // [1, 16384, 16]
    const float* As = (const float*)d_in[1];   // [4, 4096, 16384]
    const float* Ws = (const float*)d_in[2];   // [4, 16, 16]
    const float* bs = (const float*)d_in[3];   // [4, 16]
    float* out = (float*)d_out;                // [1, 4096, 16]

    float* hp = (float*)d_ws;                                       // 32 MB: [32][16384][16]
    float* h  = (float*)((char*)d_ws + (size_t)32 * 1024 * 1024);   // 1 MB: [16384][16]

    // hp/h fully overwritten every call -> no memset needed despite 0xAA poison.
    k_main<<<64 * GSPLIT, 256, 0, stream>>>(As, x, hp);
    k_hsum<<<(ROWS * 16) / 256, 256, 0, stream>>>(hp, h);
    k_out<<<(N_OUT * 16) / 256, 256, 0, stream>>>(h, Ws, bs, out);
}